// Round 1
// baseline (925.179 us; speedup 1.0000x reference)
//
#include <hip/hip_runtime.h>

// UpCaps fused kernel: lhs-dilated conv (votes) + dynamic routing, one wave per
// output pixel. Shapes: x(8,16,96,96), w(5,5,16,8,16), out(8,16,192,192).
#define XH 96
#define XW 96
#define NB 8
#define CIN 16
#define NA 8
#define NC 16
#define OH 192
#define OW 192

__global__ __launch_bounds__(256) void upcaps_fused(
    const float* __restrict__ x,
    const float* __restrict__ wts,
    const int* __restrict__ nroutes,
    float* __restrict__ out)
{
  const int lane = threadIdx.x & 63;
  const int wid  = threadIdx.x >> 6;
  const int pix  = blockIdx.x * 4 + wid;       // 36864 pixels, 4 waves/block
  const int oy   = pix / OW;
  const int ox   = pix - oy * OW;
  const int b    = lane >> 3;                  // batch 0..7
  const int a    = lane & 7;                   // atom  0..7

  // -------- voting: votes[b][a][c] for c=0..15 in registers --------
  float v[16];
#pragma unroll
  for (int c = 0; c < 16; ++c) v[c] = 0.f;

  const float* xb = x + b * (CIN * XH * XW);

#pragma unroll 1
  for (int ky = 0; ky < 5; ++ky) {
    const int py = oy - 2 + ky;                // position in dilated grid
    if (py < 0 || py > 2 * XH - 2 || (py & 1)) continue;   // wave-uniform
    const int iy = py >> 1;
#pragma unroll 1
    for (int kx = 0; kx < 5; ++kx) {
      const int px = ox - 2 + kx;
      if (px < 0 || px > 2 * XW - 2 || (px & 1)) continue; // wave-uniform
      const int ix = px >> 1;
      const float* xp = xb + iy * XW + ix;
      // w layout: (((ky*5+kx)*16 + ci)*8 + a)*16 + c
      const float* wp = wts + (ky * 5 + kx) * (CIN * NA * NC) + a * NC;
#pragma unroll
      for (int ci = 0; ci < 16; ++ci) {
        const float xv = xp[ci * (XH * XW)];
        const float4* wr = (const float4*)(wp + ci * (NA * NC));
        const float4 w0 = wr[0], w1 = wr[1], w2 = wr[2], w3 = wr[3];
        v[0]  += xv * w0.x;  v[1]  += xv * w0.y;  v[2]  += xv * w0.z;  v[3]  += xv * w0.w;
        v[4]  += xv * w1.x;  v[5]  += xv * w1.y;  v[6]  += xv * w1.z;  v[7]  += xv * w1.w;
        v[8]  += xv * w2.x;  v[9]  += xv * w2.y;  v[10] += xv * w2.z;  v[11] += xv * w2.w;
        v[12] += xv * w3.x;  v[13] += xv * w3.y;  v[14] += xv * w3.z;  v[15] += xv * w3.w;
      }
    }
  }

  // -------- dynamic routing, all in registers + wave shuffles --------
  const int R = nroutes[0];
  float logit = 0.f;
  float p[16];
#pragma unroll 1
  for (int r = 0; r < R; ++r) {
    // softmax over batch axis: lanes differing in bits 3..5 (b)
    float m = logit;
    m = fmaxf(m, __shfl_xor(m, 8));
    m = fmaxf(m, __shfl_xor(m, 16));
    m = fmaxf(m, __shfl_xor(m, 32));
    const float e = expf(logit - m);
    float s = e;
    s += __shfl_xor(s, 8);
    s += __shfl_xor(s, 16);
    s += __shfl_xor(s, 32);
    const float sl = e / s;                    // softmaxed logit

    // preds[a][c] = sum_b votes[b][a][c] * sl  (allreduce over b-lanes)
#pragma unroll
    for (int c = 0; c < 16; ++c) p[c] = v[c] * sl;
#pragma unroll
    for (int c = 0; c < 16; ++c) p[c] += __shfl_xor(p[c], 8);
#pragma unroll
    for (int c = 0; c < 16; ++c) p[c] += __shfl_xor(p[c], 16);
#pragma unroll
    for (int c = 0; c < 16; ++c) p[c] += __shfl_xor(p[c], 32);

    // squash over atoms: n2[c] = sum_a preds[a][c]^2 (allreduce over a-lanes)
    float n2[16];
#pragma unroll
    for (int c = 0; c < 16; ++c) n2[c] = p[c] * p[c];
#pragma unroll
    for (int c = 0; c < 16; ++c) n2[c] += __shfl_xor(n2[c], 1);
#pragma unroll
    for (int c = 0; c < 16; ++c) n2[c] += __shfl_xor(n2[c], 2);
#pragma unroll
    for (int c = 0; c < 16; ++c) n2[c] += __shfl_xor(n2[c], 4);
#pragma unroll
    for (int c = 0; c < 16; ++c) {
      const float nrm = sqrtf(n2[c]);
      p[c] *= nrm / (1.f + n2[c]);             // == n2/((1+n2)*nrm), safe at 0
    }

    // logits = softmaxed + <votes, preds>  (skip on last iter: dead value)
    logit = sl;
    if (r + 1 < R) {
      float d = 0.f;
#pragma unroll
      for (int c = 0; c < 16; ++c) d += v[c] * p[c];
      logit += d;
    }
  }

  // -------- write preds (A,C,OH,OW); every lane stores 2 values --------
  const int c0 = b * 2;
  out[((a * NC + c0    ) * OH + oy) * OW + ox] = p[c0];
  out[((a * NC + c0 + 1) * OH + oy) * OW + ox] = p[c0 + 1];
}

extern "C" void kernel_launch(void* const* d_in, const int* in_sizes, int n_in,
                              void* d_out, int out_size, void* d_ws, size_t ws_size,
                              hipStream_t stream) {
  const float* x   = (const float*)d_in[0];
  const float* w   = (const float*)d_in[1];
  const int*   nr  = (const int*)d_in[2];
  float*       out = (float*)d_out;

  const int npix = OH * OW;                    // 36864
  dim3 grid(npix / 4);                         // 4 waves (pixels) per block
  dim3 block(256);
  upcaps_fused<<<grid, block, 0, stream>>>(x, w, nr, out);
}

// Round 2
// 405.444 us; speedup vs baseline: 2.2819x; 2.2819x over previous
//
#include <hip/hip_runtime.h>

// UpCaps fused: lhs-dilated conv (votes) + dynamic routing.
// One wave = 4 output pixels (same oy, same parity ox -> shared tap set).
// lane = b*8 + a. Shapes: x(8,16,96,96), w(5,5,16,8,16), out(8,16,192,192).
#define XH 96
#define XW 96
#define CIN 16
#define NA 8
#define NC 16
#define OH 192
#define OW 192
#define XPLANE (XH * XW)      // 9216
#define XBATCH (CIN * XPLANE) // 147456

// static select tree: p[2*b + off], off compile-time 0/1, 7 cndmask
__device__ __forceinline__ float selb(const float (&p)[16], int b, int off) {
  const bool b0 = b & 1, b1 = b & 2, b2 = b & 4;
  float s0 = b0 ? p[2 + off]  : p[0 + off];
  float s1 = b0 ? p[6 + off]  : p[4 + off];
  float s2 = b0 ? p[10 + off] : p[8 + off];
  float s3 = b0 ? p[14 + off] : p[12 + off];
  float u0 = b1 ? s1 : s0;
  float u1 = b1 ? s3 : s2;
  return b2 ? u1 : u0;
}

__global__ __launch_bounds__(256) void upcaps_fused4(
    const float* __restrict__ x,
    const float* __restrict__ wts,
    const int* __restrict__ nroutes,
    float* __restrict__ out)
{
  const int lane = threadIdx.x & 63;
  const int wid  = threadIdx.x >> 6;
  const int tile = blockIdx.x;                 // 2304 blocks, 16 pixels each
  const int oy   = tile / 12;
  const int xg   = (tile - oy * 12) * 16;
  const int oxw  = xg + (wid & 1) + ((wid >> 1) << 3); // wave pixel 0; +2,+4,+6
  const int b    = lane >> 3;
  const int a    = lane & 7;
  const int e    = oxw & 1;

  // -------- voting: v[j][c] = votes for pixel j --------
  float v[4][16];
#pragma unroll
  for (int j = 0; j < 4; ++j)
#pragma unroll
    for (int c = 0; c < 16; ++c) v[j][c] = 0.f;

  const float* xb = x + b * XBATCH;

  for (int ky = 0; ky < 5; ++ky) {
    const int py = oy - 2 + ky;
    if (py < 0 || py > 2 * XH - 2 || (py & 1)) continue;   // wave-uniform
    const int iy = py >> 1;
    const int xrow = iy * XW;
    for (int kx = e; kx < 5; kx += 2) {                    // parity-matched taps
      const int ix0 = (oxw - 2 + kx) >> 1;                 // pixel j uses ix0+j
      float msk[4];
      int   ixc[4];
#pragma unroll
      for (int j = 0; j < 4; ++j) {
        const int ix = ix0 + j;
        msk[j] = (ix >= 0 && ix < XW) ? 1.f : 0.f;
        ixc[j] = min(max(ix, 0), XW - 1);
      }
      const float* wp = wts + (ky * 5 + kx) * (CIN * NA * NC) + a * NC;
#pragma unroll 4
      for (int ci = 0; ci < CIN; ++ci) {
        const float* xp = xb + ci * XPLANE + xrow;
        float xv[4];
#pragma unroll
        for (int j = 0; j < 4; ++j) xv[j] = xp[ixc[j]] * msk[j];
        const float4* wr = (const float4*)(wp + ci * (NA * NC));
        const float4 w0 = wr[0], w1 = wr[1], w2 = wr[2], w3 = wr[3];
#pragma unroll
        for (int j = 0; j < 4; ++j) {
          const float xj = xv[j];
          v[j][0]  += xj * w0.x;  v[j][1]  += xj * w0.y;
          v[j][2]  += xj * w0.z;  v[j][3]  += xj * w0.w;
          v[j][4]  += xj * w1.x;  v[j][5]  += xj * w1.y;
          v[j][6]  += xj * w1.z;  v[j][7]  += xj * w1.w;
          v[j][8]  += xj * w2.x;  v[j][9]  += xj * w2.y;
          v[j][10] += xj * w2.z;  v[j][11] += xj * w2.w;
          v[j][12] += xj * w3.x;  v[j][13] += xj * w3.y;
          v[j][14] += xj * w3.z;  v[j][15] += xj * w3.w;
        }
      }
    }
  }

  // -------- routing: pixel pairs interleaved for ILP --------
  const int R = nroutes[0];
  const int c0 = b * 2;

#pragma unroll
  for (int jp = 0; jp < 2; ++jp) {
    float p0[16], p1[16];
    float lg0 = 0.f, lg1 = 0.f;
#pragma unroll 1
    for (int r = 0; r < R; ++r) {
      float sl0, sl1;
      if (r == 0) {
        sl0 = sl1 = 0.125f;                    // softmax of zeros over 8 batches
      } else {
        float m0 = lg0, m1 = lg1;
        m0 = fmaxf(m0, __shfl_xor(m0, 8));  m1 = fmaxf(m1, __shfl_xor(m1, 8));
        m0 = fmaxf(m0, __shfl_xor(m0, 16)); m1 = fmaxf(m1, __shfl_xor(m1, 16));
        m0 = fmaxf(m0, __shfl_xor(m0, 32)); m1 = fmaxf(m1, __shfl_xor(m1, 32));
        float e0 = __expf(lg0 - m0), e1 = __expf(lg1 - m1);
        float s0 = e0, s1 = e1;
        s0 += __shfl_xor(s0, 8);  s1 += __shfl_xor(s1, 8);
        s0 += __shfl_xor(s0, 16); s1 += __shfl_xor(s1, 16);
        s0 += __shfl_xor(s0, 32); s1 += __shfl_xor(s1, 32);
        sl0 = e0 / s0; sl1 = e1 / s1;
      }

      // preds partials + allreduce over batch lanes (xor 8,16,32)
#pragma unroll
      for (int c = 0; c < 16; ++c) { p0[c] = v[2*jp][c] * sl0; p1[c] = v[2*jp+1][c] * sl1; }
#pragma unroll
      for (int c = 0; c < 16; ++c) { p0[c] += __shfl_xor(p0[c], 8);  p1[c] += __shfl_xor(p1[c], 8); }
#pragma unroll
      for (int c = 0; c < 16; ++c) { p0[c] += __shfl_xor(p0[c], 16); p1[c] += __shfl_xor(p1[c], 16); }
#pragma unroll
      for (int c = 0; c < 16; ++c) { p0[c] += __shfl_xor(p0[c], 32); p1[c] += __shfl_xor(p1[c], 32); }

      // squash: norm^2 over atoms (xor 1,2,4), then scale
      float n0[16], n1[16];
#pragma unroll
      for (int c = 0; c < 16; ++c) { n0[c] = p0[c] * p0[c]; n1[c] = p1[c] * p1[c]; }
#pragma unroll
      for (int c = 0; c < 16; ++c) { n0[c] += __shfl_xor(n0[c], 1); n1[c] += __shfl_xor(n1[c], 1); }
#pragma unroll
      for (int c = 0; c < 16; ++c) { n0[c] += __shfl_xor(n0[c], 2); n1[c] += __shfl_xor(n1[c], 2); }
#pragma unroll
      for (int c = 0; c < 16; ++c) { n0[c] += __shfl_xor(n0[c], 4); n1[c] += __shfl_xor(n1[c], 4); }
#pragma unroll
      for (int c = 0; c < 16; ++c) {
        const float r0n = sqrtf(n0[c]), r1n = sqrtf(n1[c]);
        p0[c] *= r0n / (1.f + n0[c]);          // == n2/((1+n2)*nrm), safe at 0
        p1[c] *= r1n / (1.f + n1[c]);
      }

      // logits = softmaxed + <votes, preds>  (dead on last round)
      lg0 = sl0; lg1 = sl1;
      if (r + 1 < R) {
        float d0 = 0.f, d1 = 0.f;
#pragma unroll
        for (int c = 0; c < 16; ++c) { d0 += v[2*jp][c] * p0[c]; d1 += v[2*jp+1][c] * p1[c]; }
        lg0 += d0; lg1 += d1;
      }
    }

    // -------- write: lane stores preds (a, 2b) and (a, 2b+1), 2 pixels --------
    const int ox0 = oxw + 4 * jp;
    float* o = out + ((a * NC + c0) * OH + oy) * OW;
    o[ox0]          = selb(p0, b, 0);
    o[OW * OH + ox0]= 0.f; // placeholder overwritten below (avoid compiler merging) 
    o[OW * OH + ox0]= selb(p0, b, 1);
    o[ox0 + 2]      = selb(p1, b, 0);
    o[OW * OH + ox0 + 2] = selb(p1, b, 1);
  }
}

extern "C" void kernel_launch(void* const* d_in, const int* in_sizes, int n_in,
                              void* d_out, int out_size, void* d_ws, size_t ws_size,
                              hipStream_t stream) {
  const float* x   = (const float*)d_in[0];
  const float* w   = (const float*)d_in[1];
  const int*   nr  = (const int*)d_in[2];
  float*       out = (float*)d_out;

  dim3 grid((OH * OW) / 16);                   // 2304 blocks, 16 pixels each
  dim3 block(256);
  upcaps_fused4<<<grid, block, 0, stream>>>(x, w, nr, out);
}

// Round 3
// 384.867 us; speedup vs baseline: 2.4039x; 1.0535x over previous
//
#include <hip/hip_runtime.h>

// UpCaps fused: lhs-dilated conv (votes) + dynamic routing.
// One wave = 4 output pixels (same oy, same parity ox -> shared tap set).
// lane = b*8 + a. Shapes: x(8,16,96,96), w(5,5,16,8,16), out(8,16,192,192).
#define XH 96
#define XW 96
#define CIN 16
#define NA 8
#define NC 16
#define OH 192
#define OW 192
#define XPLANE (XH * XW)      // 9216
#define XBATCH (CIN * XPLANE) // 147456

// static select tree: p[2*b + off], off compile-time 0/1, 7 cndmask
__device__ __forceinline__ float selb(const float (&p)[16], int b, int off) {
  const bool b0 = b & 1, b1 = b & 2, b2 = b & 4;
  float s0 = b0 ? p[2 + off]  : p[0 + off];
  float s1 = b0 ? p[6 + off]  : p[4 + off];
  float s2 = b0 ? p[10 + off] : p[8 + off];
  float s3 = b0 ? p[14 + off] : p[12 + off];
  float u0 = b1 ? s1 : s0;
  float u1 = b1 ? s3 : s2;
  return b2 ? u1 : u0;
}

// block = 256 threads = 4 waves; min 3 blocks/CU -> VGPR cap ~168, no LDS spill
__global__ __launch_bounds__(256, 3) void upcaps_fused4(
    const float* __restrict__ x,
    const float* __restrict__ wts,
    const int* __restrict__ nroutes,
    float* __restrict__ out)
{
  const int lane = threadIdx.x & 63;
  const int wid  = threadIdx.x >> 6;
  const int tile = blockIdx.x;                 // 2304 blocks, 16 pixels each
  const int oy   = tile / 12;
  const int xg   = (tile - oy * 12) * 16;
  const int oxw  = xg + (wid & 1) + ((wid >> 1) << 3); // wave pixel 0; +2,+4,+6
  const int b    = lane >> 3;
  const int a    = lane & 7;
  const int e    = oxw & 1;

  // -------- voting: v[j][c] = votes for pixel j --------
  float v[4][16];
#pragma unroll
  for (int j = 0; j < 4; ++j)
#pragma unroll
    for (int c = 0; c < 16; ++c) v[j][c] = 0.f;

  const float* xb = x + b * XBATCH;

  for (int ky = 0; ky < 5; ++ky) {
    const int py = oy - 2 + ky;
    if (py < 0 || py > 2 * XH - 2 || (py & 1)) continue;   // wave-uniform
    const int iy = py >> 1;
    const int xrow = iy * XW;
    for (int kx = e; kx < 5; kx += 2) {                    // parity-matched taps
      const int ix0 = (oxw - 2 + kx) >> 1;                 // pixel j uses ix0+j
      float msk[4];
      int   ixc[4];
#pragma unroll
      for (int j = 0; j < 4; ++j) {
        const int ix = ix0 + j;
        msk[j] = (ix >= 0 && ix < XW) ? 1.f : 0.f;
        ixc[j] = min(max(ix, 0), XW - 1);
      }
      const float* wp = wts + (ky * 5 + kx) * (CIN * NA * NC) + a * NC;
#pragma unroll 4
      for (int ci = 0; ci < CIN; ++ci) {
        const float* xp = xb + ci * XPLANE + xrow;
        float xv[4];
#pragma unroll
        for (int j = 0; j < 4; ++j) xv[j] = xp[ixc[j]] * msk[j];
        const float4* wr = (const float4*)(wp + ci * (NA * NC));
        const float4 w0 = wr[0], w1 = wr[1], w2 = wr[2], w3 = wr[3];
#pragma unroll
        for (int j = 0; j < 4; ++j) {
          const float xj = xv[j];
          v[j][0]  += xj * w0.x;  v[j][1]  += xj * w0.y;
          v[j][2]  += xj * w0.z;  v[j][3]  += xj * w0.w;
          v[j][4]  += xj * w1.x;  v[j][5]  += xj * w1.y;
          v[j][6]  += xj * w1.z;  v[j][7]  += xj * w1.w;
          v[j][8]  += xj * w2.x;  v[j][9]  += xj * w2.y;
          v[j][10] += xj * w2.z;  v[j][11] += xj * w2.w;
          v[j][12] += xj * w3.x;  v[j][13] += xj * w3.y;
          v[j][14] += xj * w3.z;  v[j][15] += xj * w3.w;
        }
      }
    }
  }

  // -------- routing: pixel pairs interleaved; squash fused per-channel --------
  const int R = nroutes[0];
  const int c0 = b * 2;

#pragma unroll
  for (int jp = 0; jp < 2; ++jp) {
    const int j0 = 2 * jp, j1 = 2 * jp + 1;
    float p0[16], p1[16];
    float lg0 = 0.f, lg1 = 0.f;
#pragma unroll 1
    for (int r = 0; r < R; ++r) {
      float sl0, sl1;
      if (r == 0) {
        sl0 = sl1 = 0.125f;                    // softmax of zeros over 8 batches
      } else {
        float m0 = lg0, m1 = lg1;
        m0 = fmaxf(m0, __shfl_xor(m0, 8));  m1 = fmaxf(m1, __shfl_xor(m1, 8));
        m0 = fmaxf(m0, __shfl_xor(m0, 16)); m1 = fmaxf(m1, __shfl_xor(m1, 16));
        m0 = fmaxf(m0, __shfl_xor(m0, 32)); m1 = fmaxf(m1, __shfl_xor(m1, 32));
        float e0 = __expf(lg0 - m0), e1 = __expf(lg1 - m1);
        float s0 = e0, s1 = e1;
        s0 += __shfl_xor(s0, 8);  s1 += __shfl_xor(s1, 8);
        s0 += __shfl_xor(s0, 16); s1 += __shfl_xor(s1, 16);
        s0 += __shfl_xor(s0, 32); s1 += __shfl_xor(s1, 32);
        sl0 = e0 * __builtin_amdgcn_rcpf(s0);  // s>=e>0
        sl1 = e1 * __builtin_amdgcn_rcpf(s1);
      }

      // per-channel: preds allreduce over b, squash norm over a, scale, dot
      float d0 = 0.f, d1 = 0.f;
#pragma unroll
      for (int c = 0; c < 16; ++c) {
        float q0 = v[j0][c] * sl0, q1 = v[j1][c] * sl1;
        q0 += __shfl_xor(q0, 8);  q1 += __shfl_xor(q1, 8);
        q0 += __shfl_xor(q0, 16); q1 += __shfl_xor(q1, 16);
        q0 += __shfl_xor(q0, 32); q1 += __shfl_xor(q1, 32);
        float n0 = q0 * q0, n1 = q1 * q1;
        n0 += __shfl_xor(n0, 1);  n1 += __shfl_xor(n1, 1);
        n0 += __shfl_xor(n0, 2);  n1 += __shfl_xor(n1, 2);
        n0 += __shfl_xor(n0, 4);  n1 += __shfl_xor(n1, 4);
        // scale = sqrt(n2)/(1+n2); rcp arg >= 1, safe; sqrtf(0)=0 keeps q=0
        q0 *= sqrtf(n0) * __builtin_amdgcn_rcpf(1.f + n0);
        q1 *= sqrtf(n1) * __builtin_amdgcn_rcpf(1.f + n1);
        p0[c] = q0; p1[c] = q1;
        d0 += v[j0][c] * q0;
        d1 += v[j1][c] * q1;
      }

      lg0 = sl0; lg1 = sl1;
      if (r + 1 < R) { lg0 += d0; lg1 += d1; }  // dead on last round
    }

    // -------- write: lane stores preds (a, 2b) and (a, 2b+1), 2 pixels --------
    const int ox0 = oxw + 4 * jp;
    float* o = out + ((a * NC + c0) * OH + oy) * OW;
    o[ox0]               = selb(p0, b, 0);
    o[OW * OH + ox0]     = selb(p0, b, 1);
    o[ox0 + 2]           = selb(p1, b, 0);
    o[OW * OH + ox0 + 2] = selb(p1, b, 1);
  }
}

extern "C" void kernel_launch(void* const* d_in, const int* in_sizes, int n_in,
                              void* d_out, int out_size, void* d_ws, size_t ws_size,
                              hipStream_t stream) {
  const float* x   = (const float*)d_in[0];
  const float* w   = (const float*)d_in[1];
  const int*   nr  = (const int*)d_in[2];
  float*       out = (float*)d_out;

  dim3 grid((OH * OW) / 16);                   // 2304 blocks, 16 pixels each
  dim3 block(256);
  upcaps_fused4<<<grid, block, 0, stream>>>(x, w, nr, out);
}

// Round 4
// 354.628 us; speedup vs baseline: 2.6089x; 1.0853x over previous
//
#include <hip/hip_runtime.h>

// UpCaps fused: lhs-dilated conv (votes) + dynamic routing.
// One wave = 4 output pixels (same oy, same parity ox -> shared tap set).
// lane = b*8 + a. Shapes: x(8,16,96,96), w(5,5,16,8,16), out(8,16,192,192).
// All per-thread arrays are statically indexed (rule #20): routing keeps NO
// p[] array -- per-channel q is a scalar, output channels captured by cndmask.
#define XH 96
#define XW 96
#define CIN 16
#define NA 8
#define NC 16
#define OH 192
#define OW 192
#define XPLANE (XH * XW)      // 9216
#define XBATCH (CIN * XPLANE) // 147456

// routes two pixels' routing loops interleaved; va/vb bound to compile-time
// sub-arrays of v so every index is static. Outputs: this lane's channels
// (c0, c0+1) of final preds for each pixel.
__device__ __forceinline__ void route_pair(
    const float (&va)[16], const float (&vb)[16],
    int R, int c0,
    float& oA0, float& oA1, float& oB0, float& oB1)
{
  float lg0 = 0.f, lg1 = 0.f;
#pragma unroll 1
  for (int r = 0; r < R; ++r) {
    float sl0, sl1;
    if (r == 0) {
      sl0 = sl1 = 0.125f;                      // softmax of zeros over 8 batches
    } else {
      float m0 = lg0, m1 = lg1;
      m0 = fmaxf(m0, __shfl_xor(m0, 8));  m1 = fmaxf(m1, __shfl_xor(m1, 8));
      m0 = fmaxf(m0, __shfl_xor(m0, 16)); m1 = fmaxf(m1, __shfl_xor(m1, 16));
      m0 = fmaxf(m0, __shfl_xor(m0, 32)); m1 = fmaxf(m1, __shfl_xor(m1, 32));
      float e0 = __expf(lg0 - m0), e1 = __expf(lg1 - m1);
      float s0 = e0, s1 = e1;
      s0 += __shfl_xor(s0, 8);  s1 += __shfl_xor(s1, 8);
      s0 += __shfl_xor(s0, 16); s1 += __shfl_xor(s1, 16);
      s0 += __shfl_xor(s0, 32); s1 += __shfl_xor(s1, 32);
      sl0 = e0 * __builtin_amdgcn_rcpf(s0);    // s >= e > 0
      sl1 = e1 * __builtin_amdgcn_rcpf(s1);
    }

    float d0 = 0.f, d1 = 0.f;
#pragma unroll
    for (int c = 0; c < 16; ++c) {
      // preds[a][c]: allreduce over batch lanes (xor 8,16,32)
      float q0 = va[c] * sl0, q1 = vb[c] * sl1;
      q0 += __shfl_xor(q0, 8);  q1 += __shfl_xor(q1, 8);
      q0 += __shfl_xor(q0, 16); q1 += __shfl_xor(q1, 16);
      q0 += __shfl_xor(q0, 32); q1 += __shfl_xor(q1, 32);
      // squash: norm^2 over atom lanes (xor 1,2,4)
      float n0 = q0 * q0, n1 = q1 * q1;
      n0 += __shfl_xor(n0, 1);  n1 += __shfl_xor(n1, 1);
      n0 += __shfl_xor(n0, 2);  n1 += __shfl_xor(n1, 2);
      n0 += __shfl_xor(n0, 4);  n1 += __shfl_xor(n1, 4);
      // scale = sqrt(n2)/(1+n2); rcp arg >= 1; sqrtf(0)=0 keeps q=0
      q0 *= sqrtf(n0) * __builtin_amdgcn_rcpf(1.f + n0);
      q1 *= sqrtf(n1) * __builtin_amdgcn_rcpf(1.f + n1);
      // capture this lane's two output channels (c is compile-time constant)
      if (c == c0)     { oA0 = q0; oB0 = q1; }
      if (c == c0 + 1) { oA1 = q0; oB1 = q1; }
      d0 += va[c] * q0;
      d1 += vb[c] * q1;
    }

    lg0 = sl0; lg1 = sl1;
    if (r + 1 < R) { lg0 += d0; lg1 += d1; }   // dead value on last round
  }
}

__global__ __launch_bounds__(256, 3) void upcaps_fused4(
    const float* __restrict__ x,
    const float* __restrict__ wts,
    const int* __restrict__ nroutes,
    float* __restrict__ out)
{
  const int lane = threadIdx.x & 63;
  const int wid  = threadIdx.x >> 6;
  const int tile = blockIdx.x;                 // 2304 blocks, 16 pixels each
  const int oy   = tile / 12;
  const int xg   = (tile - oy * 12) * 16;
  const int oxw  = xg + (wid & 1) + ((wid >> 1) << 3); // wave pixel 0; +2,+4,+6
  const int b    = lane >> 3;
  const int a    = lane & 7;
  const int e    = oxw & 1;

  // -------- voting: v[j][c] = votes for pixel oxw+2j --------
  float v[4][16];
#pragma unroll
  for (int j = 0; j < 4; ++j)
#pragma unroll
    for (int c = 0; c < 16; ++c) v[j][c] = 0.f;

  const float* xb = x + b * XBATCH;

  for (int ky = 0; ky < 5; ++ky) {
    const int py = oy - 2 + ky;
    if (py < 0 || py > 2 * XH - 2 || (py & 1)) continue;   // wave-uniform
    const int iy = py >> 1;
    const float* xrow = xb + iy * XW;
    for (int kx = e; kx < 5; kx += 2) {                    // parity-matched taps
      const int ix0 = (oxw - 2 + kx) >> 1;                 // pixel j uses ix0+j
      const bool interior = (ix0 >= 0) && (ix0 + 3 < XW);  // wave-uniform-ish
      const float* wp = wts + (ky * 5 + kx) * (CIN * NA * NC) + a * NC;
#pragma unroll 2
      for (int ci = 0; ci < CIN; ++ci) {
        const float* xp = xrow + ci * XPLANE;
        float xv[4];
        if (interior) {
#pragma unroll
          for (int j = 0; j < 4; ++j) xv[j] = xp[ix0 + j];
        } else {
#pragma unroll
          for (int j = 0; j < 4; ++j) {
            const int ix = ix0 + j;
            const bool ok = (ix >= 0) && (ix < XW);
            xv[j] = ok ? xp[min(max(ix, 0), XW - 1)] : 0.f;
          }
        }
        const float4* wr = (const float4*)(wp + ci * (NA * NC));
        const float4 w0 = wr[0], w1 = wr[1], w2 = wr[2], w3 = wr[3];
#pragma unroll
        for (int j = 0; j < 4; ++j) {
          const float xj = xv[j];
          v[j][0]  += xj * w0.x;  v[j][1]  += xj * w0.y;
          v[j][2]  += xj * w0.z;  v[j][3]  += xj * w0.w;
          v[j][4]  += xj * w1.x;  v[j][5]  += xj * w1.y;
          v[j][6]  += xj * w1.z;  v[j][7]  += xj * w1.w;
          v[j][8]  += xj * w2.x;  v[j][9]  += xj * w2.y;
          v[j][10] += xj * w2.z;  v[j][11] += xj * w2.w;
          v[j][12] += xj * w3.x;  v[j][13] += xj * w3.y;
          v[j][14] += xj * w3.z;  v[j][15] += xj * w3.w;
        }
      }
    }
  }

  // -------- routing (2 pixel-pairs, interleaved chains) --------
  const int R  = nroutes[0];
  const int c0 = b * 2;

  float pA0, pA1, pB0, pB1;
  route_pair(v[0], v[1], R, c0, pA0, pA1, pB0, pB1);
  float pC0, pC1, pD0, pD1;
  route_pair(v[2], v[3], R, c0, pC0, pC1, pD0, pD1);

  // -------- write: lane stores preds (a, 2b) and (a, 2b+1), 4 pixels --------
  float* o = out + ((a * NC + c0) * OH + oy) * OW + oxw;
  o[0] = pA0;  o[2] = pB0;  o[4] = pC0;  o[6] = pD0;
  o += OH * OW;
  o[0] = pA1;  o[2] = pB1;  o[4] = pC1;  o[6] = pD1;
}

extern "C" void kernel_launch(void* const* d_in, const int* in_sizes, int n_in,
                              void* d_out, int out_size, void* d_ws, size_t ws_size,
                              hipStream_t stream) {
  const float* x   = (const float*)d_in[0];
  const float* w   = (const float*)d_in[1];
  const int*   nr  = (const int*)d_in[2];
  float*       out = (float*)d_out;

  dim3 grid((OH * OW) / 16);                   // 2304 blocks, 16 pixels each
  dim3 block(256);
  upcaps_fused4<<<grid, block, 0, stream>>>(x, w, nr, out);
}

// Round 5
// 339.853 us; speedup vs baseline: 2.7223x; 1.0435x over previous
//
#include <hip/hip_runtime.h>

// UpCaps fused: lhs-dilated conv (votes) + dynamic routing.
// One wave = 6 output pixels (same oy, same parity ox -> shared tap set;
// x row segment hoisted across the 2-3 kx taps). lane = b*8 + a.
// Shapes: x(8,16,96,96), w(5,5,16,8,16), out(8,16,192,192).
// All per-thread arrays statically indexed (rule #20): no LDS demotion.
#define XH 96
#define XW 96
#define CIN 16
#define NA 8
#define NC 16
#define OH 192
#define OW 192
#define XPLANE (XH * XW)      // 9216
#define XBATCH (CIN * XPLANE) // 147456

// routes two pixels' routing loops interleaved; va/vb bound to compile-time
// sub-arrays of v so every index is static. Outputs: this lane's channels
// (c0, c0+1) of final preds for each pixel.
__device__ __forceinline__ void route_pair(
    const float (&va)[16], const float (&vb)[16],
    int R, int c0,
    float& oA0, float& oA1, float& oB0, float& oB1)
{
  float lg0 = 0.f, lg1 = 0.f;
#pragma unroll 1
  for (int r = 0; r < R; ++r) {
    float sl0, sl1;
    if (r == 0) {
      sl0 = sl1 = 0.125f;                      // softmax of zeros over 8 batches
    } else {
      float m0 = lg0, m1 = lg1;
      m0 = fmaxf(m0, __shfl_xor(m0, 8));  m1 = fmaxf(m1, __shfl_xor(m1, 8));
      m0 = fmaxf(m0, __shfl_xor(m0, 16)); m1 = fmaxf(m1, __shfl_xor(m1, 16));
      m0 = fmaxf(m0, __shfl_xor(m0, 32)); m1 = fmaxf(m1, __shfl_xor(m1, 32));
      float e0 = __expf(lg0 - m0), e1 = __expf(lg1 - m1);
      float s0 = e0, s1 = e1;
      s0 += __shfl_xor(s0, 8);  s1 += __shfl_xor(s1, 8);
      s0 += __shfl_xor(s0, 16); s1 += __shfl_xor(s1, 16);
      s0 += __shfl_xor(s0, 32); s1 += __shfl_xor(s1, 32);
      sl0 = e0 * __builtin_amdgcn_rcpf(s0);    // s >= e > 0
      sl1 = e1 * __builtin_amdgcn_rcpf(s1);
    }

    float d0 = 0.f, d1 = 0.f;
#pragma unroll
    for (int c = 0; c < 16; ++c) {
      // preds[a][c]: allreduce over batch lanes (xor 8,16,32)
      float q0 = va[c] * sl0, q1 = vb[c] * sl1;
      q0 += __shfl_xor(q0, 8);  q1 += __shfl_xor(q1, 8);
      q0 += __shfl_xor(q0, 16); q1 += __shfl_xor(q1, 16);
      q0 += __shfl_xor(q0, 32); q1 += __shfl_xor(q1, 32);
      // squash: norm^2 over atom lanes (xor 1,2,4)
      float n0 = q0 * q0, n1 = q1 * q1;
      n0 += __shfl_xor(n0, 1);  n1 += __shfl_xor(n1, 1);
      n0 += __shfl_xor(n0, 2);  n1 += __shfl_xor(n1, 2);
      n0 += __shfl_xor(n0, 4);  n1 += __shfl_xor(n1, 4);
      // scale = sqrt(n2)/(1+n2); rcp arg >= 1; sqrtf(0)=0 keeps q=0
      q0 *= sqrtf(n0) * __builtin_amdgcn_rcpf(1.f + n0);
      q1 *= sqrtf(n1) * __builtin_amdgcn_rcpf(1.f + n1);
      // capture this lane's two output channels (c is compile-time constant)
      if (c == c0)     { oA0 = q0; oB0 = q1; }
      if (c == c0 + 1) { oA1 = q0; oB1 = q1; }
      d0 += va[c] * q0;
      d1 += vb[c] * q1;
    }

    lg0 = sl0; lg1 = sl1;
    if (r + 1 < R) { lg0 += d0; lg1 += d1; }   // dead value on last round
  }
}

__global__ __launch_bounds__(256, 3) void upcaps_fused6(
    const float* __restrict__ x,
    const float* __restrict__ wts,
    const int* __restrict__ nroutes,
    float* __restrict__ out)
{
  const int lane = threadIdx.x & 63;
  const int wid  = threadIdx.x >> 6;
  const int tile = blockIdx.x;                 // 1536 blocks, 24 pixels each
  const int oy   = tile >> 3;
  const int xg   = (tile & 7) * 24;
  // waves 0,1: even/odd parity over [xg, xg+11]; waves 2,3 over [xg+12, xg+23]
  const int oxw  = xg + (wid & 1) + (wid >> 1) * 12;   // pixels oxw + 2j, j<6
  const int b    = lane >> 3;
  const int a    = lane & 7;
  const int e    = oxw & 1;
  const int ixb  = (oxw - 2 + e) >> 1;         // even argument, exact halving

  // -------- voting: v[j][c] = votes for pixel oxw+2j --------
  float v[6][16];
#pragma unroll
  for (int j = 0; j < 6; ++j)
#pragma unroll
    for (int c = 0; c < 16; ++c) v[j][c] = 0.f;

  const float* xb = x + b * XBATCH;
  // tap (ky, kx=e+2t), pixel j: ix = ixb + t + j  (t<=2, j<=5 -> xr[8])
  const bool interior = (ixb >= 0) && (ixb + 7 < XW);

  for (int ky = 0; ky < 5; ++ky) {
    const int py = oy - 2 + ky;
    if (py < 0 || py > 2 * XH - 2 || (py & 1)) continue;   // wave-uniform
    const float* xrow = xb + (py >> 1) * XW;
#pragma unroll 1
    for (int ci = 0; ci < CIN; ++ci) {
      const float* xp = xrow + ci * XPLANE;
      float xr[8];
      if (interior) {
#pragma unroll
        for (int k = 0; k < 8; ++k) xr[k] = xp[ixb + k];
      } else {
#pragma unroll
        for (int k = 0; k < 8; ++k) {
          const int ix = ixb + k;
          const bool ok = (ix >= 0) && (ix < XW);
          xr[k] = ok ? xp[min(max(ix, 0), XW - 1)] : 0.f;
        }
      }
#pragma unroll
      for (int t = 0; t < 3; ++t) {
        if (t == 2 && e) continue;             // odd parity: only kx=1,3
        const int kx = e + 2 * t;
        const float4* wr = (const float4*)(wts + ((ky * 5 + kx) * CIN + ci) * (NA * NC) + a * NC);
        const float4 w0 = wr[0], w1 = wr[1], w2 = wr[2], w3 = wr[3];
#pragma unroll
        for (int j = 0; j < 6; ++j) {
          const float xj = xr[t + j];
          v[j][0]  += xj * w0.x;  v[j][1]  += xj * w0.y;
          v[j][2]  += xj * w0.z;  v[j][3]  += xj * w0.w;
          v[j][4]  += xj * w1.x;  v[j][5]  += xj * w1.y;
          v[j][6]  += xj * w1.z;  v[j][7]  += xj * w1.w;
          v[j][8]  += xj * w2.x;  v[j][9]  += xj * w2.y;
          v[j][10] += xj * w2.z;  v[j][11] += xj * w2.w;
          v[j][12] += xj * w3.x;  v[j][13] += xj * w3.y;
          v[j][14] += xj * w3.z;  v[j][15] += xj * w3.w;
        }
      }
    }
  }

  // -------- routing (3 pixel-pairs, each pair's chains interleaved) --------
  const int R  = nroutes[0];
  const int c0 = b * 2;

  float pc0[6], pc1[6];
  route_pair(v[0], v[1], R, c0, pc0[0], pc1[0], pc0[1], pc1[1]);
  route_pair(v[2], v[3], R, c0, pc0[2], pc1[2], pc0[3], pc1[3]);
  route_pair(v[4], v[5], R, c0, pc0[4], pc1[4], pc0[5], pc1[5]);

  // -------- write: lane stores preds (a, 2b) and (a, 2b+1), 6 pixels --------
  float* o0 = out + ((a * NC + c0) * OH + oy) * OW + oxw;
  float* o1 = o0 + OH * OW;
#pragma unroll
  for (int j = 0; j < 6; ++j) {
    o0[2 * j] = pc0[j];
    o1[2 * j] = pc1[j];
  }
}

extern "C" void kernel_launch(void* const* d_in, const int* in_sizes, int n_in,
                              void* d_out, int out_size, void* d_ws, size_t ws_size,
                              hipStream_t stream) {
  const float* x   = (const float*)d_in[0];
  const float* w   = (const float*)d_in[1];
  const int*   nr  = (const int*)d_in[2];
  float*       out = (float*)d_out;

  dim3 grid((OH * OW) / 24);                   // 1536 blocks, 24 pixels each
  dim3 block(256);
  upcaps_fused6<<<grid, block, 0, stream>>>(x, w, nr, out);
}

// Round 6
// 145.458 us; speedup vs baseline: 6.3605x; 2.3364x over previous
//
#include <hip/hip_runtime.h>

// UpCaps fused, transposed lanes: lane = a*8 + cg (cg = c/2); each lane holds
// votes for all 8 batches of its (a, c=2cg..2cg+1). Softmax over b is
// lane-local; preds is 16 lane-local FMAs; only squash (over a: xor 8,16,32)
// and the logit update (over cg: xor 1,2,4) need shuffles.
// x is repacked into d_ws as xp[ci][iy][ixp][b] (ix padded by 1 left / 5
// right) so conv x-reads are wave-uniform 32B loads with zero edge branches.
// Output goes through an 8KB LDS block transpose -> full-64B-line stores.
// Shapes: x(8,16,96,96), w(5,5,16,8,16), out(8,16,192,192).
#define XH 96
#define XW 96
#define CIN 16
#define NA 8
#define NC 16
#define OH 192
#define OW 192
#define WP 102                        // padded width: ix in [-1,100] -> ixp 0..101
#define PADN (CIN * XH * WP * 8)      // 1,253,376 floats

__global__ __launch_bounds__(256) void pad_x(const float* __restrict__ x,
                                             float* __restrict__ xp) {
  int idx = blockIdx.x * 256 + threadIdx.x;
  if (idx >= PADN) return;
  int b   = idx & 7;
  int t   = idx >> 3;
  int ixp = t % WP;
  int t2  = t / WP;
  int iy  = t2 % XH;
  int ci  = t2 / XH;
  int ix  = ixp - 1;
  float v = 0.f;
  if (ix >= 0 && ix < XW)
    v = x[((b * CIN + ci) * XH + iy) * XW + ix];
  xp[idx] = v;
}

// routes two pixels interleaved; va/vb = votes[b][i] for this lane's (a,c).
// On exit qa/qb hold the final squashed preds for this lane's two channels.
__device__ __forceinline__ void route_pair(
    const float (&va)[8][2], const float (&vb)[8][2],
    int R, float (&qa)[2], float (&qb)[2])
{
  float lga[8], lgb[8];
#pragma unroll
  for (int b = 0; b < 8; ++b) { lga[b] = 0.f; lgb[b] = 0.f; }
#pragma unroll 1
  for (int r = 0; r < R; ++r) {
    float sla[8], slb[8];
    if (r == 0) {
#pragma unroll
      for (int b = 0; b < 8; ++b) { sla[b] = 0.125f; slb[b] = 0.125f; }
    } else {
      // softmax over batch: fully lane-local (8 regs)
      float ma = lga[0], mb = lgb[0];
#pragma unroll
      for (int b = 1; b < 8; ++b) { ma = fmaxf(ma, lga[b]); mb = fmaxf(mb, lgb[b]); }
      float sa = 0.f, sb = 0.f;
#pragma unroll
      for (int b = 0; b < 8; ++b) {
        sla[b] = __expf(lga[b] - ma); sa += sla[b];
        slb[b] = __expf(lgb[b] - mb); sb += slb[b];
      }
      const float ira = __builtin_amdgcn_rcpf(sa);   // sa >= 1 > 0
      const float irb = __builtin_amdgcn_rcpf(sb);
#pragma unroll
      for (int b = 0; b < 8; ++b) { sla[b] *= ira; slb[b] *= irb; }
    }

    // preds[a][c] = sum_b votes * sl : lane-local FMA chain
    qa[0] = 0.f; qa[1] = 0.f; qb[0] = 0.f; qb[1] = 0.f;
#pragma unroll
    for (int b = 0; b < 8; ++b) {
      qa[0] += va[b][0] * sla[b];  qa[1] += va[b][1] * sla[b];
      qb[0] += vb[b][0] * slb[b];  qb[1] += vb[b][1] * slb[b];
    }

    // squash: norm^2 over atoms = reduce over a-lanes (bits 3..5)
#pragma unroll
    for (int i = 0; i < 2; ++i) {
      float na = qa[i] * qa[i], nb = qb[i] * qb[i];
      na += __shfl_xor(na, 8);  nb += __shfl_xor(nb, 8);
      na += __shfl_xor(na, 16); nb += __shfl_xor(nb, 16);
      na += __shfl_xor(na, 32); nb += __shfl_xor(nb, 32);
      qa[i] *= sqrtf(na) * __builtin_amdgcn_rcpf(1.f + na);  // sqrt(n)/(1+n)
      qb[i] *= sqrtf(nb) * __builtin_amdgcn_rcpf(1.f + nb);
    }

    // logits = softmaxed + sum_c votes*preds (reduce over cg-lanes, bits 0..2)
    if (r + 1 < R) {
#pragma unroll
      for (int b = 0; b < 8; ++b) {
        float da = va[b][0] * qa[0] + va[b][1] * qa[1];
        float db = vb[b][0] * qb[0] + vb[b][1] * qb[1];
        da += __shfl_xor(da, 1);  db += __shfl_xor(db, 1);
        da += __shfl_xor(da, 2);  db += __shfl_xor(db, 2);
        da += __shfl_xor(da, 4);  db += __shfl_xor(db, 4);
        lga[b] = sla[b] + da;     lgb[b] = slb[b] + db;
      }
    }
  }
}

__global__ __launch_bounds__(256, 4) void upcaps_tr(
    const float* __restrict__ xp,    // padded [ci][iy][ixp][b]
    const float* __restrict__ wts,
    const int* __restrict__ nroutes,
    float* __restrict__ out)
{
  __shared__ float lds_out[16 * 128];   // [pxi][a*16+c]

  const int lane = threadIdx.x & 63;
  const int wid  = threadIdx.x >> 6;
  const int tile = blockIdx.x;          // 2304 blocks, 16 px each
  const int oy   = tile / 12;
  const int xg   = (tile - oy * 12) * 16;            // 64B-line aligned
  const int pxb  = (wid & 1) + ((wid >> 1) << 3);    // wave px: pxb + 2j
  const int oxw  = xg + pxb;
  const int a    = lane >> 3;
  const int cg   = lane & 7;
  const int e    = oxw & 1;
  // conv input col: ix = ixb + t + j,  t,j in [0,2]x[0,3]
  const int ixp0 = __builtin_amdgcn_readfirstlane(((oxw - 2 + e) >> 1) + 1);
  const bool use_t2 = (__builtin_amdgcn_readfirstlane(e) == 0);
  const int wlane = a * NC + cg * 2;    // per-lane float offset into w[..][a][c]

  float acc[4][8][2];
#pragma unroll
  for (int j = 0; j < 4; ++j)
#pragma unroll
    for (int b = 0; b < 8; ++b) { acc[j][b][0] = 0.f; acc[j][b][1] = 0.f; }

  for (int ky = 0; ky < 5; ++ky) {
    const int py = oy - 2 + ky;
    if (py < 0 || py > 2 * XH - 2 || (py & 1)) continue;   // wave-uniform
    const int iy = py >> 1;
#pragma unroll 2
    for (int ci = 0; ci < CIN; ++ci) {
      const float* xrow = xp + ((ci * XH + iy) * WP + ixp0) * 8;  // uniform
      // weights for taps kx = e + 2t
      float2 wv0, wv1, wv2;
      {
        const float* w0 = wts + ((ky * 5 + e)     * CIN + ci) * (NA * NC) + wlane;
        const float* w1 = wts + ((ky * 5 + e + 2) * CIN + ci) * (NA * NC) + wlane;
        wv0 = *(const float2*)w0;
        wv1 = *(const float2*)w1;
        wv2 = make_float2(0.f, 0.f);
        if (use_t2) {
          const float* w2 = wts + ((ky * 5 + 4) * CIN + ci) * (NA * NC) + wlane;
          wv2 = *(const float2*)w2;
        }
      }
#pragma unroll
      for (int ir = 0; ir < 6; ++ir) {
        if (ir == 5 && !use_t2) continue;          // odd parity needs ir<=4
        const float4 xlo = *(const float4*)(xrow + ir * 8);
        const float4 xhi = *(const float4*)(xrow + ir * 8 + 4);
        const float xv[8] = {xlo.x, xlo.y, xlo.z, xlo.w,
                             xhi.x, xhi.y, xhi.z, xhi.w};
        if (ir <= 3) {                             // t=0, j=ir
#pragma unroll
          for (int b = 0; b < 8; ++b) {
            acc[ir][b][0] += xv[b] * wv0.x;  acc[ir][b][1] += xv[b] * wv0.y;
          }
        }
        if (ir >= 1 && ir <= 4) {                  // t=1, j=ir-1
#pragma unroll
          for (int b = 0; b < 8; ++b) {
            acc[ir-1][b][0] += xv[b] * wv1.x;  acc[ir-1][b][1] += xv[b] * wv1.y;
          }
        }
        if (ir >= 2 && use_t2) {                   // t=2, j=ir-2
#pragma unroll
          for (int b = 0; b < 8; ++b) {
            acc[ir-2][b][0] += xv[b] * wv2.x;  acc[ir-2][b][1] += xv[b] * wv2.y;
          }
        }
      }
    }
  }

  // -------- routing (2 interleaved pairs) --------
  const int R = nroutes[0];
  float q0[2], q1[2], q2[2], q3[2];
  route_pair(acc[0], acc[1], R, q0, q1);
  route_pair(acc[2], acc[3], R, q2, q3);

  // -------- stage results to LDS: [pxi][a*16+c] --------
  const int lbase = a * NC + cg * 2;
  *(float2*)&lds_out[(pxb    ) * 128 + lbase] = make_float2(q0[0], q0[1]);
  *(float2*)&lds_out[(pxb + 2) * 128 + lbase] = make_float2(q1[0], q1[1]);
  *(float2*)&lds_out[(pxb + 4) * 128 + lbase] = make_float2(q2[0], q2[1]);
  *(float2*)&lds_out[(pxb + 6) * 128 + lbase] = make_float2(q3[0], q3[1]);
  __syncthreads();

  // -------- coalesced output: thread -> (row r = a*16+c, half h) --------
  const int t = threadIdx.x;
  const int r = t >> 1, h = t & 1;
  float4 f0, f1;
  f0.x = lds_out[(h * 8 + 0) * 128 + r];
  f0.y = lds_out[(h * 8 + 1) * 128 + r];
  f0.z = lds_out[(h * 8 + 2) * 128 + r];
  f0.w = lds_out[(h * 8 + 3) * 128 + r];
  f1.x = lds_out[(h * 8 + 4) * 128 + r];
  f1.y = lds_out[(h * 8 + 5) * 128 + r];
  f1.z = lds_out[(h * 8 + 6) * 128 + r];
  f1.w = lds_out[(h * 8 + 7) * 128 + r];
  float* op = out + r * (OH * OW) + oy * OW + xg + h * 8;
  *(float4*)op       = f0;
  *(float4*)(op + 4) = f1;
}

extern "C" void kernel_launch(void* const* d_in, const int* in_sizes, int n_in,
                              void* d_out, int out_size, void* d_ws, size_t ws_size,
                              hipStream_t stream) {
  const float* x   = (const float*)d_in[0];
  const float* w   = (const float*)d_in[1];
  const int*   nr  = (const int*)d_in[2];
  float*       out = (float*)d_out;
  float*       xp  = (float*)d_ws;       // needs PADN*4 = 5,013,504 bytes

  pad_x<<<(PADN + 255) / 256, 256, 0, stream>>>(x, xp);
  upcaps_tr<<<(OH * OW) / 16, 256, 0, stream>>>(xp, w, nr, out);
}